// Round 5
// baseline (270.418 us; speedup 1.0000x reference)
//
#include <hip/hip_runtime.h>

// Policy net fully fused: GRU(64 steps) -> comm-mean -> 8-agent attention -> MLP heads.
// K0: one-time weight->bf16 MFMA-fragment conversion into d_ws.
// K1: one wave = 16 seqs = 2 complete batches; GRU + ALL head phases wave-local
//     (zero __syncthreads). 2048 waves.
// __launch_bounds__(256,1): the ONLY config observed to allocate >128 VGPRs
// (R1: 220, no spill). (256,2) and waves_per_eu(2,2) both pinned 128 + spilled
// ~35-40 MB of scratch per launch (R3/R4 WRITE_SIZE). Live set ~200 < 256 so
// we still expect 2 waves/SIMD.

typedef float f32x4 __attribute__((ext_vector_type(4)));
typedef short bf16x8 __attribute__((ext_vector_type(8)));

#define MFMA16 __builtin_amdgcn_mfma_f32_16x16x32_bf16
#define LOG2E 1.44269504088896f
#define INV_SQRT_D 0.09449111825230679f

__device__ __forceinline__ short f2bf(float f) {          // RNE (cold paths)
    union { float f; unsigned u; } v; v.f = f;
    unsigned r = v.u + 0x7fffu + ((v.u >> 16) & 1u);
    return (short)(r >> 16);
}
__device__ __forceinline__ short f2bf_hu(float f) {       // round-half-up (hot paths)
    union { float f; unsigned u; } v; v.f = f;
    return (short)((v.u + 0x8000u) >> 16);
}
__device__ __forceinline__ float fexp2(float x) { return __builtin_amdgcn_exp2f(x); }
__device__ __forceinline__ float frcp(float x)  { return __builtin_amdgcn_rcpf(x); }
__device__ __forceinline__ void lds_fence() {             // cross-lane LDS RAW guard
    __asm__ __volatile__("s_waitcnt lgkmcnt(0)" ::: "memory");
}

// ---------------------------------------------------------------------------
// Kernel 0: head weights -> bf16 B-fragments (MFMA lane layout).
// fid: 0..5 Wm | 6..33 Wq | 34..61 Wk | 62..89 Wv | 90..121 W1 | 122..153 W2 |
//      154..157 heads.  Storage: wf[(fid*64+lane)*8 .. +7]
// ---------------------------------------------------------------------------
__global__ void conv_kernel(
    const float* __restrict__ Wm, const float* __restrict__ Wq,
    const float* __restrict__ Wk, const float* __restrict__ Wv,
    const float* __restrict__ W1, const float* __restrict__ W2,
    const float* __restrict__ Wmean, const float* __restrict__ Wval,
    unsigned short* __restrict__ wf)
{
    int gid = blockIdx.x * 256 + threadIdx.x;
    if (gid >= 158 * 64) return;
    int fid = gid >> 6, lane = gid & 63;
    int l15 = lane & 15, q = lane >> 4;

    short out[8] = {0,0,0,0,0,0,0,0};
    if (fid < 154) {
        const float* W; int nrows, Klim, idx;
        if (fid < 6)        { W = Wm; nrows = 32;  Klim = 80;  idx = fid;       }
        else if (fid < 34)  { W = Wq; nrows = 112; Klim = 112; idx = fid - 6;   }
        else if (fid < 62)  { W = Wk; nrows = 112; Klim = 112; idx = fid - 34;  }
        else if (fid < 90)  { W = Wv; nrows = 112; Klim = 112; idx = fid - 62;  }
        else if (fid < 122) { W = W1; nrows = 128; Klim = 112; idx = fid - 90;  }
        else                { W = W2; nrows = 128; Klim = 128; idx = fid - 122; }
        int nch = (fid < 6) ? 3 : 4;
        int ct = idx / nch, ch = idx - ct * nch;
        int g = ct * 16 + l15, k0 = ch * 32 + q * 8;
        if (g < nrows && (k0 + 8) <= Klim) {
            const float* wp = W + (size_t)g * Klim + k0;
            #pragma unroll
            for (int u = 0; u < 8; ++u) out[u] = f2bf(wp[u]);
        }
    } else {
        int ch = fid - 154, k0 = ch * 32 + q * 8;
        const float* wp = (l15 == 0) ? Wmean : (l15 == 1) ? (Wmean + 128)
                          : (l15 == 2) ? Wval : nullptr;
        if (wp) {
            #pragma unroll
            for (int u = 0; u < 8; ++u) out[u] = f2bf(wp[k0 + u]);
        }
    }
    *(bf16x8*)(wf + ((size_t)fid * 64 + lane) * 8) = *(bf16x8*)out;
}

// ---------------------------------------------------------------------------
// Kernel 1: fused policy. grid 512 x 256 -> 2048 waves x 16 seqs.
// ---------------------------------------------------------------------------
__global__ __launch_bounds__(256, 1)
void policy_kernel(
    const float* __restrict__ seq,    // [32768][64][4]
    const float* __restrict__ W_ih, const float* __restrict__ W_hh,
    const float* __restrict__ b_ih, const float* __restrict__ b_hh,
    const float* __restrict__ embed,
    const unsigned short* __restrict__ wf,
    const float* __restrict__ bm, const float* __restrict__ bq,
    const float* __restrict__ bk, const float* __restrict__ bv,
    const float* __restrict__ b1, const float* __restrict__ b2,
    const float* __restrict__ bmean, const float* __restrict__ bval,
    float* __restrict__ out)          // mean [32768][2] then val [32768]
{
    __shared__ short R1s[4][16][136];  // h(0..63)|id(64..79)|c(80..111)|pad -> O
    __shared__ short R2s[4][16][136];  // Q -> h3
    __shared__ short R3s[4][16][136];  // K -> h4
    __shared__ short Vts[4][114][20];  // V^T [Dcol][agent], zero-padded
    __shared__ short Pbs[4][16][40];   // attention probs (A-layout rows)

    const int tid  = threadIdx.x;
    const int wv   = tid >> 6;
    const int lane = tid & 63;
    const int l15  = lane & 15;
    const int q    = lane >> 4;
    const int seqbase = (blockIdx.x * 4 + wv) * 16;   // 16 seqs = 2 batches

    short (*R1)[136] = R1s[wv];
    short (*R2)[136] = R2s[wv];
    short (*R3)[136] = R3s[wv];
    short (*Vt)[20]  = Vts[wv];
    short (*Pb)[40]  = Pbs[wv];
    const f32x4 zz = {0.f, 0.f, 0.f, 0.f};

    {   // zero this wave's LDS slices (wave-local)
        int* p;
        p = (int*)&R1[0][0]; for (int i = lane; i < 1088; i += 64) p[i] = 0;
        p = (int*)&R2[0][0]; for (int i = lane; i < 1088; i += 64) p[i] = 0;
        p = (int*)&R3[0][0]; for (int i = lane; i < 1088; i += 64) p[i] = 0;
        p = (int*)&Vt[0][0]; for (int i = lane; i < 1140; i += 64) p[i] = 0;
        p = (int*)&Pb[0][0]; for (int i = lane; i < 320;  i += 64) p[i] = 0;
    }
    {   // id embedding -> R1 cols 64..79 (agent row i uses embed[i&7])
        int row = lane >> 2, j0 = (lane & 3) * 4;
        f32x4 e = *(const f32x4*)(embed + (row & 7) * 16 + j0);
        #pragma unroll
        for (int u = 0; u < 4; ++u) R1[row][64 + j0 + u] = f2bf(e[u]);
    }

    // ---- GRU weight fragments (pre-scaled so exps are exp2(acc) directly) ----
    // Bh[12][2]: W_hh (96 regs) | B2[8]: r,z x-proj + combined bias (32 regs)
    // B2x[4]: n-gate x-proj + b_ih_n (16 regs) | bhh_n[4]: b_hh_n scalars (VALU)
    const float sc_rz = -LOG2E;
    const float sc_n  = 2.0f * LOG2E;
    bf16x8 Bh[12][2], B2[8], B2x[4];
    float bhh_n[4];
    #pragma unroll
    for (int j = 0; j < 12; ++j) {
        int g = j * 16 + l15;
        float s = (j < 8) ? sc_rz : sc_n;
        #pragma unroll
        for (int c = 0; c < 2; ++c) {
            const float* wp = W_hh + g * 64 + c * 32 + q * 8;
            bf16x8 f;
            #pragma unroll
            for (int u = 0; u < 8; ++u) f[u] = f2bf(wp[u] * s);
            Bh[j][c] = f;
        }
    }
    #pragma unroll
    for (int j = 0; j < 8; ++j) {
        int g = j * 16 + l15;
        bf16x8 f2 = {0,0,0,0,0,0,0,0};
        if (q == 0) {
            #pragma unroll
            for (int u = 0; u < 4; ++u) f2[u] = f2bf(W_ih[g * 4 + u] * sc_rz);
            f2[4] = f2bf((b_ih[g] + b_hh[g]) * sc_rz);
        }
        B2[j] = f2;
    }
    #pragma unroll
    for (int j2 = 0; j2 < 4; ++j2) {
        int g = 128 + j2 * 16 + l15;
        bf16x8 f = {0,0,0,0,0,0,0,0};
        if (q == 0) {
            #pragma unroll
            for (int u = 0; u < 4; ++u) f[u] = f2bf(W_ih[g * 4 + u] * sc_n);
            f[4] = f2bf(b_ih[g] * sc_n);
        }
        B2x[j2] = f;
        bhh_n[j2] = b_hh[g] * sc_n;
    }
    lds_fence();

    // ---- GRU main loop: h lives in R1 cols 0..63 ----
    const short onebf = 0x3f80;
    float h[4][4];
    #pragma unroll
    for (int j = 0; j < 4; ++j)
        #pragma unroll
        for (int r = 0; r < 4; ++r) h[j][r] = 0.f;

    f32x4 xc = *(const f32x4*)(seq + (size_t)(seqbase + l15) * 256);

    for (int t = 0; t < 64; ++t) {
        int tn = (t < 63) ? t + 1 : 63;
        f32x4 xnext = *(const f32x4*)(seq + (size_t)(seqbase + l15) * 256 + tn * 4);

        bf16x8 A0 = *(const bf16x8*)&R1[l15][q * 8];
        bf16x8 A1 = *(const bf16x8*)&R1[l15][32 + q * 8];
        bf16x8 A2;
        A2[0] = f2bf_hu(xc[0]); A2[1] = f2bf_hu(xc[1]);
        A2[2] = f2bf_hu(xc[2]); A2[3] = f2bf_hu(xc[3]);
        A2[4] = onebf; A2[5] = 0; A2[6] = 0; A2[7] = 0;

        #pragma unroll
        for (int j = 0; j < 4; ++j) {
            f32x4 ar = MFMA16(A2, B2[j], zz, 0, 0, 0);
            ar = MFMA16(A0, Bh[j][0], ar, 0, 0, 0);
            ar = MFMA16(A1, Bh[j][1], ar, 0, 0, 0);
            f32x4 az = MFMA16(A2, B2[4 + j], zz, 0, 0, 0);
            az = MFMA16(A0, Bh[4 + j][0], az, 0, 0, 0);
            az = MFMA16(A1, Bh[4 + j][1], az, 0, 0, 0);
            f32x4 an = MFMA16(A0, Bh[8 + j][0], zz, 0, 0, 0);
            an = MFMA16(A1, Bh[8 + j][1], an, 0, 0, 0);
            f32x4 ax = MFMA16(A2, B2x[j], zz, 0, 0, 0);

            #pragma unroll
            for (int r = 0; r < 4; ++r) {
                float e_r  = fexp2(ar[r]);                 // exp(-pre_r)
                float rg   = frcp(1.f + e_r);
                float e_z  = fexp2(az[r]);                 // exp(-pre_z)
                float anb  = an[r] + bhh_n[j];             // 2log2e * hn
                float npre = fmaf(rg, anb, ax[r]);         // 2log2e*(xn + r*hn)
                float e_t  = fexp2(npre);
                float tp   = e_t + 1.f;
                float tm   = e_t - 1.f;
                float hv   = h[j][r];
                float num  = fmaf(hv, tp, e_z * tm);
                float den  = fmaf(tp, e_z, tp);
                float hnew = num * frcp(den);
                h[j][r] = hnew;
                R1[q * 4 + r][16 * j + l15] = f2bf_hu(hnew);
            }
        }
        xc = xnext;
    }
    lds_fence();

    // ---- head phases, all wave-local ----
    auto ld = [&](int fid) -> bf16x8 {
        return *(const bf16x8*)(wf + ((size_t)fid * 64 + lane) * 8);
    };

    // P1+P2: msgs = [h|id] @ Wm^T ; comm mean over own batch; c -> R1 cols 80..111
    #pragma unroll
    for (int ct = 0; ct < 2; ++ct) {
        f32x4 acc = zz;
        #pragma unroll
        for (int ch = 0; ch < 3; ++ch) {
            bf16x8 a = *(const bf16x8*)&R1[l15][ch * 32 + q * 8];
            acc = MFMA16(a, ld(ct * 3 + ch), acc, 0, 0, 0);
        }
        float s = acc[0] + acc[1] + acc[2] + acc[3];   // rows q*4..q*4+3
        s += __shfl_xor(s, 16, 64);                    // + other q of same batch
        float cv = 0.125f * s + bm[16 * ct + l15];
        short cb = f2bf_hu(cv);
        #pragma unroll
        for (int r = 0; r < 4; ++r) R1[q * 4 + r][80 + 16 * ct + l15] = cb;
    }
    lds_fence();

    // P3: Q,K,V (K=112 pad 128); Q pre-scaled; V stored transposed
    #pragma unroll
    for (int ct = 0; ct < 7; ++ct) {
        f32x4 aq = zz, ak = zz, av = zz;
        #pragma unroll
        for (int ch = 0; ch < 4; ++ch) {
            bf16x8 a = *(const bf16x8*)&R1[l15][ch * 32 + q * 8];
            aq = MFMA16(a, ld(6  + ct * 4 + ch), aq, 0, 0, 0);
            ak = MFMA16(a, ld(34 + ct * 4 + ch), ak, 0, 0, 0);
            av = MFMA16(a, ld(62 + ct * 4 + ch), av, 0, 0, 0);
        }
        int col = 16 * ct + l15;
        float biq = bq[col], bik = bk[col], biv = bv[col];
        #pragma unroll
        for (int r = 0; r < 4; ++r) {
            int row = q * 4 + r;
            R2[row][col] = f2bf_hu((aq[r] + biq) * INV_SQRT_D);
            R3[row][col] = f2bf_hu(ak[r] + bik);
            Vt[col][row] = f2bf_hu(av[r] + biv);
        }
    }
    lds_fence();

    // P4: S = Q K^T (16x16 = 2 batches block-diagonal); 8-wide softmax via shfl
    {
        f32x4 acc = zz;
        #pragma unroll
        for (int ch = 0; ch < 4; ++ch) {
            bf16x8 a = *(const bf16x8*)&R2[l15][ch * 32 + q * 8];
            bf16x8 b = *(const bf16x8*)&R3[l15][ch * 32 + q * 8];
            acc = MFMA16(a, b, acc, 0, 0, 0);
        }
        bool collow = (l15 < 8);
        #pragma unroll
        for (int r = 0; r < 4; ++r) {
            int rl = q * 4 + r;
            bool valid = ((rl < 8) == collow);
            float v = acc[r];
            float m = v;
            m = fmaxf(m, __shfl_xor(m, 1, 64));
            m = fmaxf(m, __shfl_xor(m, 2, 64));
            m = fmaxf(m, __shfl_xor(m, 4, 64));
            float e = fexp2(LOG2E * (v - m));
            float s = e;
            s += __shfl_xor(s, 1, 64);
            s += __shfl_xor(s, 2, 64);
            s += __shfl_xor(s, 4, 64);
            float pv = valid ? e * frcp(s) : 0.f;
            Pb[rl][l15] = f2bf_hu(pv);
        }
    }
    lds_fence();

    // P5: O = P V (K=32; P cols 16..31 zero) -> R1
    {
        bf16x8 a = *(const bf16x8*)&Pb[l15][q * 8];
        #pragma unroll
        for (int ct = 0; ct < 7; ++ct) {
            bf16x8 b = *(const bf16x8*)&Vt[16 * ct + l15][q * 8];
            f32x4 acc = MFMA16(a, b, zz, 0, 0, 0);
            #pragma unroll
            for (int r = 0; r < 4; ++r) R1[q * 4 + r][16 * ct + l15] = f2bf_hu(acc[r]);
        }
    }
    lds_fence();

    // P6: h3 = relu(O @ W1^T + b1)  K=112 pad 128 -> R2
    #pragma unroll
    for (int ct = 0; ct < 8; ++ct) {
        f32x4 acc = zz;
        #pragma unroll
        for (int ch = 0; ch < 4; ++ch) {
            bf16x8 a = *(const bf16x8*)&R1[l15][ch * 32 + q * 8];
            acc = MFMA16(a, ld(90 + ct * 4 + ch), acc, 0, 0, 0);
        }
        float bias = b1[16 * ct + l15];
        #pragma unroll
        for (int r = 0; r < 4; ++r)
            R2[q * 4 + r][16 * ct + l15] = f2bf_hu(fmaxf(acc[r] + bias, 0.f));
    }
    lds_fence();

    // P7: h4 = relu(h3 @ W2^T + b2)  K=128 -> R3
    #pragma unroll
    for (int ct = 0; ct < 8; ++ct) {
        f32x4 acc = zz;
        #pragma unroll
        for (int ch = 0; ch < 4; ++ch) {
            bf16x8 a = *(const bf16x8*)&R2[l15][ch * 32 + q * 8];
            acc = MFMA16(a, ld(122 + ct * 4 + ch), acc, 0, 0, 0);
        }
        float bias = b2[16 * ct + l15];
        #pragma unroll
        for (int r = 0; r < 4; ++r)
            R3[q * 4 + r][16 * ct + l15] = f2bf_hu(fmaxf(acc[r] + bias, 0.f));
    }
    lds_fence();

    // P8: heads (K=128): cols 0,1 -> mean; col 2 -> value
    {
        f32x4 acc = zz;
        #pragma unroll
        for (int ch = 0; ch < 4; ++ch) {
            bf16x8 a = *(const bf16x8*)&R3[l15][ch * 32 + q * 8];
            acc = MFMA16(a, ld(154 + ch), acc, 0, 0, 0);
        }
        if (l15 < 3) {
            float bias = (l15 == 0) ? bmean[0] : (l15 == 1) ? bmean[1] : bval[0];
            #pragma unroll
            for (int r = 0; r < 4; ++r) {
                int A = seqbase + q * 4 + r;
                float v = acc[r] + bias;
                if (l15 < 2) out[(size_t)A * 2 + l15] = v;
                else         out[65536 + A] = v;
            }
        }
    }
}

// ---------------------------------------------------------------------------
extern "C" void kernel_launch(void* const* d_in, const int* in_sizes, int n_in,
                              void* d_out, int out_size, void* d_ws, size_t ws_size,
                              hipStream_t stream) {
    const float* seq   = (const float*)d_in[0];
    const float* W_ih  = (const float*)d_in[1];
    const float* W_hh  = (const float*)d_in[2];
    const float* b_ih  = (const float*)d_in[3];
    const float* b_hh  = (const float*)d_in[4];
    const float* embed = (const float*)d_in[5];
    const float* Wm    = (const float*)d_in[6];
    const float* bm    = (const float*)d_in[7];
    const float* Wq    = (const float*)d_in[8];
    const float* bq    = (const float*)d_in[9];
    const float* Wk    = (const float*)d_in[10];
    const float* bk    = (const float*)d_in[11];
    const float* Wv    = (const float*)d_in[12];
    const float* bv    = (const float*)d_in[13];
    const float* W1    = (const float*)d_in[14];
    const float* b1    = (const float*)d_in[15];
    const float* W2    = (const float*)d_in[16];
    const float* b2    = (const float*)d_in[17];
    const float* Wmean = (const float*)d_in[18];
    const float* bmean = (const float*)d_in[19];
    const float* Wval  = (const float*)d_in[20];
    const float* bval  = (const float*)d_in[21];

    unsigned short* wf = (unsigned short*)d_ws;   // 158 frags * 64 lanes * 16 B

    conv_kernel<<<40, 256, 0, stream>>>(Wm, Wq, Wk, Wv, W1, W2, Wmean, Wval, wf);
    policy_kernel<<<512, 256, 0, stream>>>(seq, W_ih, W_hh, b_ih, b_hh, embed, wf,
                                           bm, bq, bk, bv, b1, b2, bmean, bval,
                                           (float*)d_out);
}

// Round 6
// 236.150 us; speedup vs baseline: 1.1451x; 1.1451x over previous
//
#include <hip/hip_runtime.h>

// Policy net fully fused: GRU(64 steps) -> comm-mean -> 8-agent attention -> MLP heads.
// K0: one-time weight->bf16 MFMA-fragment conversion into d_ws.
// K1: one wave = 16 seqs = 2 complete batches; GRU + ALL head phases wave-local.
// Register budget (measured R3-R5): 2 waves/SIMD needs arch+acc <= 256 total
// (~128+128). Chunk-2 B-fragments (48 regs, wave-invariant) live in LDS C2,
// re-read per step via launder-blocked ds_read_b128. V is computed after
// softmax into R2 (no standalone Vt buffer) to keep LDS <= 80 KB for 2 WG/CU.

typedef float f32x4 __attribute__((ext_vector_type(4)));
typedef short bf16x8 __attribute__((ext_vector_type(8)));

#define MFMA16 __builtin_amdgcn_mfma_f32_16x16x32_bf16
#define LOG2E 1.44269504088896f
#define INV_SQRT_D 0.09449111825230679f

__device__ __forceinline__ short f2bf(float f) {          // RNE (cold paths)
    union { float f; unsigned u; } v; v.f = f;
    unsigned r = v.u + 0x7fffu + ((v.u >> 16) & 1u);
    return (short)(r >> 16);
}
__device__ __forceinline__ short f2bf_hu(float f) {       // round-half-up (hot paths)
    union { float f; unsigned u; } v; v.f = f;
    return (short)((v.u + 0x8000u) >> 16);
}
__device__ __forceinline__ float fexp2(float x) { return __builtin_amdgcn_exp2f(x); }
__device__ __forceinline__ float frcp(float x)  { return __builtin_amdgcn_rcpf(x); }
__device__ __forceinline__ void lds_fence() {             // cross-lane LDS RAW guard
    __asm__ __volatile__("s_waitcnt lgkmcnt(0)" ::: "memory");
}
__device__ __forceinline__ int launder(int x) {           // block LICM/CSE on x
    __asm__ __volatile__("" : "+v"(x));
    return x;
}

// ---------------------------------------------------------------------------
// Kernel 0: head weights -> bf16 B-fragments (MFMA lane layout).
// fid: 0..5 Wm | 6..33 Wq | 34..61 Wk | 62..89 Wv | 90..121 W1 | 122..153 W2 |
//      154..157 heads.  Storage: wf[(fid*64+lane)*8 .. +7]
// ---------------------------------------------------------------------------
__global__ void conv_kernel(
    const float* __restrict__ Wm, const float* __restrict__ Wq,
    const float* __restrict__ Wk, const float* __restrict__ Wv,
    const float* __restrict__ W1, const float* __restrict__ W2,
    const float* __restrict__ Wmean, const float* __restrict__ Wval,
    unsigned short* __restrict__ wf)
{
    int gid = blockIdx.x * 256 + threadIdx.x;
    if (gid >= 158 * 64) return;
    int fid = gid >> 6, lane = gid & 63;
    int l15 = lane & 15, q = lane >> 4;

    short out[8] = {0,0,0,0,0,0,0,0};
    if (fid < 154) {
        const float* W; int nrows, Klim, idx;
        if (fid < 6)        { W = Wm; nrows = 32;  Klim = 80;  idx = fid;       }
        else if (fid < 34)  { W = Wq; nrows = 112; Klim = 112; idx = fid - 6;   }
        else if (fid < 62)  { W = Wk; nrows = 112; Klim = 112; idx = fid - 34;  }
        else if (fid < 90)  { W = Wv; nrows = 112; Klim = 112; idx = fid - 62;  }
        else if (fid < 122) { W = W1; nrows = 128; Klim = 112; idx = fid - 90;  }
        else                { W = W2; nrows = 128; Klim = 128; idx = fid - 122; }
        int nch = (fid < 6) ? 3 : 4;
        int ct = idx / nch, ch = idx - ct * nch;
        int g = ct * 16 + l15, k0 = ch * 32 + q * 8;
        if (g < nrows && (k0 + 8) <= Klim) {
            const float* wp = W + (size_t)g * Klim + k0;
            #pragma unroll
            for (int u = 0; u < 8; ++u) out[u] = f2bf(wp[u]);
        }
    } else {
        int ch = fid - 154, k0 = ch * 32 + q * 8;
        const float* wp = (l15 == 0) ? Wmean : (l15 == 1) ? (Wmean + 128)
                          : (l15 == 2) ? Wval : nullptr;
        if (wp) {
            #pragma unroll
            for (int u = 0; u < 8; ++u) out[u] = f2bf(wp[k0 + u]);
        }
    }
    *(bf16x8*)(wf + ((size_t)fid * 64 + lane) * 8) = *(bf16x8*)out;
}

// ---------------------------------------------------------------------------
// Kernel 1: fused policy. grid 512 x 256 -> 2048 waves x 16 seqs.
// ---------------------------------------------------------------------------
__global__ __launch_bounds__(256, 2)
void policy_kernel(
    const float* __restrict__ seq,    // [32768][64][4]
    const float* __restrict__ W_ih, const float* __restrict__ W_hh,
    const float* __restrict__ b_ih, const float* __restrict__ b_hh,
    const float* __restrict__ embed,
    const unsigned short* __restrict__ wf,
    const float* __restrict__ bm, const float* __restrict__ bq,
    const float* __restrict__ bk, const float* __restrict__ bv,
    const float* __restrict__ b1, const float* __restrict__ b2,
    const float* __restrict__ bmean, const float* __restrict__ bval,
    float* __restrict__ out)          // mean [32768][2] then val [32768]
{
    __shared__ short R1s[4][16][136];  // h|id|c|pad -> O
    __shared__ short R2s[4][16][136];  // Q -> V^T -> h3
    __shared__ short R3s[4][16][136];  // K -> h4
    __shared__ short Pbs[4][16][40];   // attention probs (A-layout rows)
    __shared__ short C2[12][64][8];    // GRU chunk-2 B-frags (WG-shared, 12 KB)

    const int tid  = threadIdx.x;
    const int wv   = tid >> 6;
    const int lane = tid & 63;
    const int l15  = lane & 15;
    const int q    = lane >> 4;
    const int seqbase = (blockIdx.x * 4 + wv) * 16;   // 16 seqs = 2 batches

    short (*R1)[136] = R1s[wv];
    short (*R2)[136] = R2s[wv];
    short (*R3)[136] = R3s[wv];
    short (*Pb)[40]  = Pbs[wv];
    const f32x4 zz = {0.f, 0.f, 0.f, 0.f};

    const float sc_rz = -LOG2E;
    const float sc_n  = 2.0f * LOG2E;

    {   // zero this wave's LDS slices (wave-local)
        int* p;
        p = (int*)&R1[0][0]; for (int i = lane; i < 1088; i += 64) p[i] = 0;
        p = (int*)&R2[0][0]; for (int i = lane; i < 1088; i += 64) p[i] = 0;
        p = (int*)&R3[0][0]; for (int i = lane; i < 1088; i += 64) p[i] = 0;
        p = (int*)&Pb[0][0]; for (int i = lane; i < 320;  i += 64) p[i] = 0;
    }
    {   // id embedding -> R1 cols 64..79 (agent row i uses embed[i&7])
        int row = lane >> 2, j0 = (lane & 3) * 4;
        f32x4 e = *(const f32x4*)(embed + (row & 7) * 16 + j0);
        #pragma unroll
        for (int u = 0; u < 4; ++u) R1[row][64 + j0 + u] = f2bf(e[u]);
    }

    // ---- wave 0 populates C2: chunk-2 x-proj+bias fragments (all waves share)
    if (wv == 0) {
        #pragma unroll
        for (int j = 0; j < 8; ++j) {          // r,z gates, scaled -log2e
            int g = j * 16 + l15;
            short f2[8] = {0,0,0,0,0,0,0,0};
            if (q == 0) {
                #pragma unroll
                for (int u = 0; u < 4; ++u) f2[u] = f2bf(W_ih[g * 4 + u] * sc_rz);
                f2[4] = f2bf((b_ih[g] + b_hh[g]) * sc_rz);
            }
            *(bf16x8*)&C2[j][lane][0] = *(bf16x8*)f2;
        }
        #pragma unroll
        for (int j2 = 0; j2 < 4; ++j2) {       // n gate x-part, scaled 2*log2e
            int g = 128 + j2 * 16 + l15;
            short f2[8] = {0,0,0,0,0,0,0,0};
            if (q == 0) {
                #pragma unroll
                for (int u = 0; u < 4; ++u) f2[u] = f2bf(W_ih[g * 4 + u] * sc_n);
                f2[4] = f2bf(b_ih[g] * sc_n);
            }
            *(bf16x8*)&C2[8 + j2][lane][0] = *(bf16x8*)f2;
        }
    }

    // ---- W_hh fragments in registers (96, acc-file eligible) ----
    bf16x8 Bh[12][2];
    float bhh_n[4];
    #pragma unroll
    for (int j = 0; j < 12; ++j) {
        int g = j * 16 + l15;
        float s = (j < 8) ? sc_rz : sc_n;
        #pragma unroll
        for (int c = 0; c < 2; ++c) {
            const float* wp = W_hh + g * 64 + c * 32 + q * 8;
            bf16x8 f;
            #pragma unroll
            for (int u = 0; u < 8; ++u) f[u] = f2bf(wp[u] * s);
            Bh[j][c] = f;
        }
    }
    #pragma unroll
    for (int j2 = 0; j2 < 4; ++j2)
        bhh_n[j2] = b_hh[128 + j2 * 16 + l15] * sc_n;

    __syncthreads();   // C2 + id-embed visible to all waves (once; loop is barrier-free)

    // ---- GRU main loop: h lives in R1 cols 0..63 ----
    const short onebf = 0x3f80;
    float h[4][4];
    #pragma unroll
    for (int j = 0; j < 4; ++j)
        #pragma unroll
        for (int r = 0; r < 4; ++r) h[j][r] = 0.f;

    const short* C2base = &C2[0][0][0];
    f32x4 xc = *(const f32x4*)(seq + (size_t)(seqbase + l15) * 256);

    for (int t = 0; t < 64; ++t) {
        int tn = (t < 63) ? t + 1 : 63;
        f32x4 xnext = *(const f32x4*)(seq + (size_t)(seqbase + l15) * 256 + tn * 4);

        bf16x8 A0 = *(const bf16x8*)&R1[l15][q * 8];
        bf16x8 A1 = *(const bf16x8*)&R1[l15][32 + q * 8];
        bf16x8 A2;
        A2[0] = f2bf_hu(xc[0]); A2[1] = f2bf_hu(xc[1]);
        A2[2] = f2bf_hu(xc[2]); A2[3] = f2bf_hu(xc[3]);
        A2[4] = onebf; A2[5] = 0; A2[6] = 0; A2[7] = 0;

        #pragma unroll
        for (int j = 0; j < 4; ++j) {
            // chunk-2 B-frags from LDS; offsets laundered so they can't be hoisted
            bf16x8 c2r = *(const bf16x8*)(C2base + launder(((j    ) * 64 + lane) * 8));
            bf16x8 c2z = *(const bf16x8*)(C2base + launder(((4 + j) * 64 + lane) * 8));
            bf16x8 c2n = *(const bf16x8*)(C2base + launder(((8 + j) * 64 + lane) * 8));

            f32x4 ar = MFMA16(A2, c2r, zz, 0, 0, 0);
            ar = MFMA16(A0, Bh[j][0], ar, 0, 0, 0);
            ar = MFMA16(A1, Bh[j][1], ar, 0, 0, 0);
            f32x4 az = MFMA16(A2, c2z, zz, 0, 0, 0);
            az = MFMA16(A0, Bh[4 + j][0], az, 0, 0, 0);
            az = MFMA16(A1, Bh[4 + j][1], az, 0, 0, 0);
            f32x4 an = MFMA16(A0, Bh[8 + j][0], zz, 0, 0, 0);
            an = MFMA16(A1, Bh[8 + j][1], an, 0, 0, 0);
            f32x4 ax = MFMA16(A2, c2n, zz, 0, 0, 0);

            #pragma unroll
            for (int r = 0; r < 4; ++r) {
                float e_r  = fexp2(ar[r]);                 // exp(-pre_r)
                float rg   = frcp(1.f + e_r);
                float e_z  = fexp2(az[r]);                 // exp(-pre_z)
                float anb  = an[r] + bhh_n[j];             // 2log2e * hn
                float npre = fmaf(rg, anb, ax[r]);         // 2log2e*(xn + r*hn)
                float e_t  = fexp2(npre);
                float tp   = e_t + 1.f;
                float tm   = e_t - 1.f;
                float hv   = h[j][r];
                float num  = fmaf(hv, tp, e_z * tm);
                float den  = fmaf(tp, e_z, tp);
                float hnew = num * frcp(den);
                h[j][r] = hnew;
                R1[q * 4 + r][16 * j + l15] = f2bf_hu(hnew);
            }
        }
        xc = xnext;
    }
    lds_fence();

    // ---- head phases, all wave-local ----
    auto ld = [&](int fid) -> bf16x8 {
        return *(const bf16x8*)(wf + ((size_t)fid * 64 + lane) * 8);
    };

    // P1+P2: msgs = [h|id] @ Wm^T ; comm mean over own batch; c -> R1 cols 80..111
    #pragma unroll
    for (int ct = 0; ct < 2; ++ct) {
        f32x4 acc = zz;
        #pragma unroll
        for (int ch = 0; ch < 3; ++ch) {
            bf16x8 a = *(const bf16x8*)&R1[l15][ch * 32 + q * 8];
            acc = MFMA16(a, ld(ct * 3 + ch), acc, 0, 0, 0);
        }
        float s = acc[0] + acc[1] + acc[2] + acc[3];   // rows q*4..q*4+3
        s += __shfl_xor(s, 16, 64);                    // + other q of same batch
        float cv = 0.125f * s + bm[16 * ct + l15];
        short cb = f2bf_hu(cv);
        #pragma unroll
        for (int r = 0; r < 4; ++r) R1[q * 4 + r][80 + 16 * ct + l15] = cb;
    }
    lds_fence();

    // P3: Q -> R2, K -> R3 (K=112 pad 128); Q pre-scaled by 1/sqrt(112)
    #pragma unroll
    for (int ct = 0; ct < 7; ++ct) {
        f32x4 aq = zz, ak = zz;
        #pragma unroll
        for (int ch = 0; ch < 4; ++ch) {
            bf16x8 a = *(const bf16x8*)&R1[l15][ch * 32 + q * 8];
            aq = MFMA16(a, ld(6  + ct * 4 + ch), aq, 0, 0, 0);
            ak = MFMA16(a, ld(34 + ct * 4 + ch), ak, 0, 0, 0);
        }
        int col = 16 * ct + l15;
        float biq = bq[col], bik = bk[col];
        #pragma unroll
        for (int r = 0; r < 4; ++r) {
            int row = q * 4 + r;
            R2[row][col] = f2bf_hu((aq[r] + biq) * INV_SQRT_D);
            R3[row][col] = f2bf_hu(ak[r] + bik);
        }
    }
    lds_fence();

    // P4: S = Q K^T (16x16 = 2 batches block-diagonal); 8-wide softmax via shfl
    {
        f32x4 acc = zz;
        #pragma unroll
        for (int ch = 0; ch < 4; ++ch) {
            bf16x8 a = *(const bf16x8*)&R2[l15][ch * 32 + q * 8];
            bf16x8 b = *(const bf16x8*)&R3[l15][ch * 32 + q * 8];
            acc = MFMA16(a, b, acc, 0, 0, 0);
        }
        bool collow = (l15 < 8);
        #pragma unroll
        for (int r = 0; r < 4; ++r) {
            int rl = q * 4 + r;
            bool valid = ((rl < 8) == collow);
            float v = acc[r];
            float m = v;
            m = fmaxf(m, __shfl_xor(m, 1, 64));
            m = fmaxf(m, __shfl_xor(m, 2, 64));
            m = fmaxf(m, __shfl_xor(m, 4, 64));
            float e = fexp2(LOG2E * (v - m));
            float s = e;
            s += __shfl_xor(s, 1, 64);
            s += __shfl_xor(s, 2, 64);
            s += __shfl_xor(s, 4, 64);
            float pv = valid ? e * frcp(s) : 0.f;
            Pb[rl][l15] = f2bf_hu(pv);
        }
    }
    lds_fence();

    // P5a: V-pass (hcat in R1 still live) -> V^T overlay in R2 [112][18] (Q dead)
    {
        short* VtR = &R2[0][0];
        #pragma unroll
        for (int ct = 0; ct < 7; ++ct) {
            f32x4 av = zz;
            #pragma unroll
            for (int ch = 0; ch < 4; ++ch) {
                bf16x8 a = *(const bf16x8*)&R1[l15][ch * 32 + q * 8];
                av = MFMA16(a, ld(62 + ct * 4 + ch), av, 0, 0, 0);
            }
            int col = 16 * ct + l15;
            float biv = bv[col];
            #pragma unroll
            for (int r = 0; r < 4; ++r)
                VtR[col * 18 + q * 4 + r] = f2bf_hu(av[r] + biv);
        }
    }
    lds_fence();

    // P5b: O = P V (K=32; Pb cols 16..31 zero) -> R1
    {
        const short* VtR = &R2[0][0];
        bf16x8 a = *(const bf16x8*)&Pb[l15][q * 8];
        #pragma unroll
        for (int ct = 0; ct < 7; ++ct) {
            bf16x8 b = *(const bf16x8*)(VtR + (16 * ct + l15) * 18 + q * 8);
            f32x4 acc = MFMA16(a, b, zz, 0, 0, 0);
            #pragma unroll
            for (int r = 0; r < 4; ++r) R1[q * 4 + r][16 * ct + l15] = f2bf_hu(acc[r]);
        }
    }
    lds_fence();

    // P6: h3 = relu(O @ W1^T + b1)  K=112 pad 128 -> R2 (Vt dead; all 128 cols written)
    #pragma unroll
    for (int ct = 0; ct < 8; ++ct) {
        f32x4 acc = zz;
        #pragma unroll
        for (int ch = 0; ch < 4; ++ch) {
            bf16x8 a = *(const bf16x8*)&R1[l15][ch * 32 + q * 8];
            acc = MFMA16(a, ld(90 + ct * 4 + ch), acc, 0, 0, 0);
        }
        float bias = b1[16 * ct + l15];
        #pragma unroll
        for (int r = 0; r < 4; ++r)
            R2[q * 4 + r][16 * ct + l15] = f2bf_hu(fmaxf(acc[r] + bias, 0.f));
    }
    lds_fence();

    // P7: h4 = relu(h3 @ W2^T + b2)  K=128 -> R3
    #pragma unroll
    for (int ct = 0; ct < 8; ++ct) {
        f32x4 acc = zz;
        #pragma unroll
        for (int ch = 0; ch < 4; ++ch) {
            bf16x8 a = *(const bf16x8*)&R2[l15][ch * 32 + q * 8];
            acc = MFMA16(a, ld(122 + ct * 4 + ch), acc, 0, 0, 0);
        }
        float bias = b2[16 * ct + l15];
        #pragma unroll
        for (int r = 0; r < 4; ++r)
            R3[q * 4 + r][16 * ct + l15] = f2bf_hu(fmaxf(acc[r] + bias, 0.f));
    }
    lds_fence();

    // P8: heads (K=128): cols 0,1 -> mean; col 2 -> value
    {
        f32x4 acc = zz;
        #pragma unroll
        for (int ch = 0; ch < 4; ++ch) {
            bf16x8 a = *(const bf16x8*)&R3[l15][ch * 32 + q * 8];
            acc = MFMA16(a, ld(154 + ch), acc, 0, 0, 0);
        }
        if (l15 < 3) {
            float bias = (l15 == 0) ? bmean[0] : (l15 == 1) ? bmean[1] : bval[0];
            #pragma unroll
            for (int r = 0; r < 4; ++r) {
                int A = seqbase + q * 4 + r;
                float v = acc[r] + bias;
                if (l15 < 2) out[(size_t)A * 2 + l15] = v;
                else         out[65536 + A] = v;
            }
        }
    }
}

// ---------------------------------------------------------------------------
extern "C" void kernel_launch(void* const* d_in, const int* in_sizes, int n_in,
                              void* d_out, int out_size, void* d_ws, size_t ws_size,
                              hipStream_t stream) {
    const float* seq   = (const float*)d_in[0];
    const float* W_ih  = (const float*)d_in[1];
    const float* W_hh  = (const float*)d_in[2];
    const float* b_ih  = (const float*)d_in[3];
    const float* b_hh  = (const float*)d_in[4];
    const float* embed = (const float*)d_in[5];
    const float* Wm    = (const float*)d_in[6];
    const float* bm    = (const float*)d_in[7];
    const float* Wq    = (const float*)d_in[8];
    const float* bq    = (const float*)d_in[9];
    const float* Wk    = (const float*)d_in[10];
    const float* bk    = (const float*)d_in[11];
    const float* Wv    = (const float*)d_in[12];
    const float* bv    = (const float*)d_in[13];
    const float* W1    = (const float*)d_in[14];
    const float* b1    = (const float*)d_in[15];
    const float* W2    = (const float*)d_in[16];
    const float* b2    = (const float*)d_in[17];
    const float* Wmean = (const float*)d_in[18];
    const float* bmean = (const float*)d_in[19];
    const float* Wval  = (const float*)d_in[20];
    const float* bval  = (const float*)d_in[21];

    unsigned short* wf = (unsigned short*)d_ws;   // 158 frags * 64 lanes * 16 B

    conv_kernel<<<40, 256, 0, stream>>>(Wm, Wq, Wk, Wv, W1, W2, Wmean, Wval, wf);
    policy_kernel<<<512, 256, 0, stream>>>(seq, W_ih, W_hh, b_ih, b_hh, embed, wf,
                                           bm, bq, bk, bv, b1, b2, bmean, bval,
                                           (float*)d_out);
}